// Round 8
// baseline (193.020 us; speedup 1.0000x reference)
//
#include <hip/hip_runtime.h>

typedef unsigned short u16;
typedef __bf16 bf16x8 __attribute__((ext_vector_type(8)));
typedef float f32x4 __attribute__((ext_vector_type(4)));

__device__ inline u16 f2bf(float f) {
    union { float f; unsigned int u; } a; a.f = f;
    unsigned int u = a.u + 0x7fffu + ((a.u >> 16) & 1u);
    return (u16)(u >> 16);
}
// truncate f32 -> bf16 bits; returns truncated value as f32
__device__ __forceinline__ float truncbf(float f, u16& h) {
    union { float f; unsigned int u; } a; a.f = f;
    a.u &= 0xffff0000u;
    h = (u16)(a.u >> 16);
    return a.f;
}

// async global->LDS, 16B per lane. LDS side is wave-uniform base + lane*16.
__device__ __forceinline__ void cp16(const void* g, void* l) {
    __builtin_amdgcn_global_load_lds(
        (const __attribute__((address_space(1))) unsigned int*)g,
        (__attribute__((address_space(3))) unsigned int*)l, 16, 0, 0);
}

// -------- prep: fuse x-cast + both weight transposes (1 launch) --------
__global__ __launch_bounds__(256) void prep(
    const float* __restrict__ x, const float* __restrict__ wq,
    const float* __restrict__ wo, u16* __restrict__ xbf,
    u16* __restrict__ wtq, u16* __restrict__ wto)
{
    int bid = blockIdx.x;
    if (bid < 3072) {                      // cast x: f32 -> bf16, 8/thread
        size_t base = ((size_t)bid * 256 + threadIdx.x) * 8;
        float4 f0 = *(const float4*)&x[base];
        float4 f1 = *(const float4*)&x[base + 4];
        union { u16 s[8]; uint4 v; } t;
        t.s[0]=f2bf(f0.x); t.s[1]=f2bf(f0.y); t.s[2]=f2bf(f0.z); t.s[3]=f2bf(f0.w);
        t.s[4]=f2bf(f1.x); t.s[5]=f2bf(f1.y); t.s[6]=f2bf(f1.z); t.s[7]=f2bf(f1.w);
        *(uint4*)&xbf[base] = t.v;
        return;
    }
    __shared__ u16 tile[32][33];
    const float* in; u16* outp; int N, bx, by;
    if (bid < 3072 + 1728) { int t = bid - 3072; in = wq; outp = wtq; N = 2304; bx = t % 72; by = t / 72; }
    else                   { int t = bid - 4800; in = wo; outp = wto; N = 768;  bx = t % 24; by = t / 24; }
    int n0 = bx * 32, k0 = by * 32;
    int tx = threadIdx.x & 31, ty = threadIdx.x >> 5;
    #pragma unroll
    for (int r = ty; r < 32; r += 8)
        tile[r][tx] = f2bf(in[(size_t)(k0 + r) * N + n0 + tx]);
    __syncthreads();
    #pragma unroll
    for (int r = ty; r < 32; r += 8)
        outp[(size_t)(n0 + r) * 768 + k0 + tx] = tile[tx][r];
}

// -------- QKV GEMM: BK=32 dbuf (32 KB LDS), prefetch-first, XCD-pinned --------
// LDS tile layout: logical row R (0..127) -> packed row r'=R&63 (128 B), slot
// s = ((R>>6)*4 + kgroup) ^ (r'&7). Conflict-free b128 frags, lane-order staging.
// A bf16 [8192][768], Bt bf16 [2304][768]
// Q (*0.125*log2e) -> [b,h,n,64]; K -> [b,h,n,64]; V -> TRANSPOSED [b,h,d,n]
__global__ __launch_bounds__(256) void gemm_qkv(
    const u16* __restrict__ A, const u16* __restrict__ Bt,
    u16* __restrict__ q_out, u16* __restrict__ k_out, u16* __restrict__ v_out)
{
    const int K = 768;
    __shared__ __align__(16) u16 As[2][128 * 32];   // 8 KB per buffer
    __shared__ __align__(16) u16 Bs[2][128 * 32];

    int tid = threadIdx.x;
    int lane = tid & 63, wave = tid >> 6;
    int quad = lane >> 4, l16 = lane & 15;
    int wm = wave >> 1, wn = wave & 1;
    int id = blockIdx.x;
    int xcd = id & 7, j = id >> 3;
    int m0 = (((j & 7) << 3) + xcd) * 128;   // 64 m-tiles, XCD-pinned A slabs
    int n0 = (j >> 3) * 128;                 // 18 n-tiles

    f32x4 acc[4][4];
    #pragma unroll
    for (int i = 0; i < 4; i++)
        #pragma unroll
        for (int jj = 0; jj < 4; jj++) acc[i][jj] = (f32x4){0.f, 0.f, 0.f, 0.f};

    // staging decode: chunk c = it*256+tid -> r'=c>>3, t8=(c&7)^(r'&7), row=r'+64*(t8>>2), kgroup=t8&3
    const u16* GA[2]; const u16* GB[2];
    #pragma unroll
    for (int it = 0; it < 2; it++) {
        int c = it * 256 + tid;
        int rp = c >> 3;
        int t8 = (c & 7) ^ (rp & 7);
        int row = rp + 64 * (t8 >> 2), gk = t8 & 3;
        GA[it] = A  + (size_t)(m0 + row) * K + gk * 8;
        GB[it] = Bt + (size_t)(n0 + row) * K + gk * 8;
    }

    #define STG(kt, b)                                              \
        _Pragma("unroll")                                           \
        for (int it = 0; it < 2; it++) {                            \
            cp16(GA[it] + (kt), &As[b][(it * 256 + tid) * 8]);      \
            cp16(GB[it] + (kt), &Bs[b][(it * 256 + tid) * 8]);      \
        }

    STG(0, 0)
    for (int i = 0; i < 24; i++) {
        int b = i & 1;
        __syncthreads();                              // drains buf-b loads
        if (i + 1 < 24) { STG((i + 1) * 32, b ^ 1) }  // max slack: issue first
        bf16x8 af[4], bfr[4];
        #pragma unroll
        for (int x = 0; x < 4; x++) {
            int Ra = wm * 64 + x * 16 + l16, ra = Ra & 63;
            int sa = (((Ra >> 6) << 2) + quad) ^ (ra & 7);
            af[x] = *(const bf16x8*)&As[b][ra * 64 + sa * 8];
            int Rb = wn * 64 + x * 16 + l16, rb = Rb & 63;
            int sb = (((Rb >> 6) << 2) + quad) ^ (rb & 7);
            bfr[x] = *(const bf16x8*)&Bs[b][rb * 64 + sb * 8];
        }
        #pragma unroll
        for (int x = 0; x < 4; x++)
            #pragma unroll
            for (int y = 0; y < 4; y++)
                acc[x][y] = __builtin_amdgcn_mfma_f32_16x16x32_bf16(af[x], bfr[y], acc[x][y], 0, 0, 0);
    }
    #undef STG
    __syncthreads();   // all frag reads done before buffers become epilogue scratch

    // ---- epilogue: wave tile = 64m x 64n, one (part,h); per-wave 8 KB LDS region ----
    int M0 = m0 + wm * 64, N0 = n0 + wn * 64;
    int part = N0 >= 1536 ? 2 : (N0 >= 768 ? 1 : 0);
    int h = (N0 - part * 768) >> 6;
    int b2 = M0 >> 10, npos0 = M0 & 1023;
    u16* ep = (wave & 2) ? &Bs[wave & 1][0] : &As[wave & 1][0];

    if (part != 2) {
        float scale = (part == 0) ? 0.18033688011112042f : 1.0f;   // /8 * log2e for Q
        u16* gbase = (part == 0 ? q_out : k_out) + (((size_t)(b2 * 12 + h) * 1024 + npos0) << 6);
        #pragma unroll
        for (int i = 0; i < 4; i++)
            #pragma unroll
            for (int jj = 0; jj < 4; jj++) {
                int dd = jj * 16 + l16;
                #pragma unroll
                for (int r = 0; r < 4; r++) {
                    int np = i * 16 + quad * 4 + r;
                    ep[np * 64 + (((dd >> 3) ^ (np & 7)) * 8) + (dd & 7)] =
                        f2bf(acc[i][jj][r] * scale);
                }
            }
        #pragma unroll
        for (int t = 0; t < 8; t++) {        // per-wave region: ds order suffices
            int idx = t * 512 + lane * 8;
            int np = idx >> 6;
            int slot = ((lane & 7) ^ (np & 7));
            uint4 v = *(const uint4*)&ep[np * 64 + slot * 8];
            *(uint4*)&gbase[idx] = v;
        }
    } else {
        #pragma unroll
        for (int i = 0; i < 4; i++)
            #pragma unroll
            for (int jj = 0; jj < 4; jj++) {
                int dd = jj * 16 + l16;
                int npg = i * 2 + (quad >> 1);
                int sub = (quad & 1) * 4;
                union { u16 s[4]; uint2 v; } pk;
                #pragma unroll
                for (int r = 0; r < 4; r++) pk.s[r] = f2bf(acc[i][jj][r]);
                *(uint2*)&ep[dd * 64 + ((npg ^ (dd & 7)) * 8) + sub] = pk.v;
            }
        #pragma unroll
        for (int t = 0; t < 8; t++) {
            int dd = t * 8 + (lane >> 3);
            int npg = lane & 7;
            uint4 v = *(const uint4*)&ep[dd * 64 + ((npg ^ (dd & 7)) * 8)];
            *(uint4*)&v_out[((size_t)((b2 * 12 + h) * 64 + dd)) * 1024 + npos0 + npg * 8] = v;
        }
    }
}

// -------- attention: S^T form, 128 q/block, dbuf prefetch-first, XCD-pinned heads --------
__global__ __launch_bounds__(256) void attn128(
    u16* __restrict__ QO, const u16* __restrict__ Kg, const u16* __restrict__ Vtg)
{
    __shared__ __align__(16) u16 Ks[2][64 * 64];   // [kv][d], groups XOR-swizzled
    __shared__ __align__(16) u16 Vs[2][64 * 64];   // [d][kv], groups XOR-swizzled

    int tid = threadIdx.x;
    int lane = tid & 63, wave = tid >> 6;
    int quad = lane >> 4, l16 = lane & 15;
    int id = blockIdx.x;
    int xcd = id & 7, j = id >> 3;              // 12 heads per XCD
    int bh = xcd * 12 + (j >> 3);
    int q0 = (j & 7) * 128;
    const size_t head_base = (size_t)bh * 65536;

    size_t qoff[2];
    bf16x8 qf[2][2];
    #pragma unroll
    for (int qs = 0; qs < 2; qs++) {
        qoff[qs] = head_base + (size_t)(q0 + wave * 32 + qs * 16 + l16) * 64;
        qf[qs][0] = *(const bf16x8*)&QO[qoff[qs] + quad * 8];
        qf[qs][1] = *(const bf16x8*)&QO[qoff[qs] + 32 + quad * 8];
    }

    f32x4 Oacc[4][2];
    #pragma unroll
    for (int dt = 0; dt < 4; dt++)
        #pragma unroll
        for (int qs = 0; qs < 2; qs++) Oacc[dt][qs] = (f32x4){0.f, 0.f, 0.f, 0.f};
    float l_part[2] = {0.f, 0.f};

    int srow = tid >> 3, sg = tid & 7;
    int gs = sg ^ (srow & 7);
    const u16* GK[2]; const u16* GV[2];
    #pragma unroll
    for (int it = 0; it < 2; it++) {
        GK[it] = Kg  + head_base + (size_t)(it * 32 + srow) * 64 + gs * 8;
        GV[it] = Vtg + head_base + (size_t)(it * 32 + srow) * 1024 + gs * 8;
    }

    #define STAGE_ATT(j0, b)                                          \
        _Pragma("unroll")                                             \
        for (int it = 0; it < 2; it++) {                              \
            cp16(GK[it] + (size_t)(j0) * 64, &Ks[b][(it * 256 + tid) * 8]); \
            cp16(GV[it] + (j0),             &Vs[b][(it * 256 + tid) * 8]); \
        }

    STAGE_ATT(0, 0)
    for (int i = 0; i < 16; i++) {
        int b = i & 1;
        __syncthreads();
        if (i + 1 < 16) { STAGE_ATT((i + 1) * 64, b ^ 1) }
        bf16x8 kf[4][2];
        #pragma unroll
        for (int nt = 0; nt < 4; nt++) {
            int R = nt * 16 + l16;
            kf[nt][0] = *(const bf16x8*)&Ks[b][R * 64 + ((quad       ^ (R & 7)) * 8)];
            kf[nt][1] = *(const bf16x8*)&Ks[b][R * 64 + (((quad + 4) ^ (R & 7)) * 8)];
        }

        f32x4 s4[4][2];
        #pragma unroll
        for (int nt = 0; nt < 4; nt++)
            #pragma unroll
            for (int qs = 0; qs < 2; qs++) {
                f32x4 s = (f32x4){0.f, 0.f, 0.f, 0.f};
                s = __builtin_amdgcn_mfma_f32_16x16x32_bf16(kf[nt][0], qf[qs][0], s, 0, 0, 0);
                s = __builtin_amdgcn_mfma_f32_16x16x32_bf16(kf[nt][1], qf[qs][1], s, 0, 0, 0);
                s4[nt][qs] = s;
            }

        // p = 2^s, truncated to bf16; l sums the SAME truncated values
        u16 ph[4][2][4];
        #pragma unroll
        for (int nt = 0; nt < 4; nt++)
            #pragma unroll
            for (int qs = 0; qs < 2; qs++)
                #pragma unroll
                for (int r = 0; r < 4; r++) {
                    float p = __builtin_amdgcn_exp2f(s4[nt][qs][r]);
                    l_part[qs] += truncbf(p, ph[nt][qs][r]);
                }

        #pragma unroll
        for (int h = 0; h < 2; h++) {
            union { u16 s[8]; bf16x8 v; } pk[2];
            #pragma unroll
            for (int qs = 0; qs < 2; qs++)
                #pragma unroll
                for (int r = 0; r < 4; r++) {
                    pk[qs].s[r]     = ph[2 * h][qs][r];
                    pk[qs].s[4 + r] = ph[2 * h + 1][qs][r];
                }
            int lg0 = 4 * h + (quad >> 1), lg1 = lg0 + 2;
            int off = (quad & 1) * 4;
            #pragma unroll
            for (int dt = 0; dt < 4; dt++) {
                int drow = dt * 16 + l16;
                union { u16 s[8]; bf16x8 v; } vk;
                *(uint2*)&vk.s[0] = *(const uint2*)&Vs[b][drow * 64 + (lg0 ^ (drow & 7)) * 8 + off];
                *(uint2*)&vk.s[4] = *(const uint2*)&Vs[b][drow * 64 + (lg1 ^ (drow & 7)) * 8 + off];
                #pragma unroll
                for (int qs = 0; qs < 2; qs++)
                    Oacc[dt][qs] = __builtin_amdgcn_mfma_f32_16x16x32_bf16(vk.v, pk[qs].v, Oacc[dt][qs], 0, 0, 0);
            }
        }
    }
    #undef STAGE_ATT

    #pragma unroll
    for (int qs = 0; qs < 2; qs++) {
        float l = l_part[qs];
        l += __shfl_xor(l, 16);
        l += __shfl_xor(l, 32);
        float rl = __builtin_amdgcn_rcpf(l);
        #pragma unroll
        for (int dt = 0; dt < 4; dt++) {
            union { u16 s[4]; uint2 v; } ok;
            #pragma unroll
            for (int r = 0; r < 4; r++) ok.s[r] = f2bf(Oacc[dt][qs][r] * rl);
            *(uint2*)&QO[qoff[qs] + dt * 16 + quad * 4] = ok.v;
        }
    }
}

// -------- out-proj GEMM: BK=64 dbuf, prefetch-first, XCD-pinned --------
__global__ __launch_bounds__(256) void gemm_out(
    const u16* __restrict__ Qg, const u16* __restrict__ Bt,
    const float* __restrict__ bias, float* __restrict__ out)
{
    const int K = 768;
    __shared__ __align__(16) u16 As[2][128 * 64];
    __shared__ __align__(16) u16 Bs[2][128 * 64];

    int tid = threadIdx.x;
    int lane = tid & 63, wave = tid >> 6;
    int quad = lane >> 4, l16 = lane & 15;
    int wm = wave >> 1, wn = wave & 1;
    int id = blockIdx.x;
    int xcd = id & 7, j = id >> 3;
    int m0 = (((j & 7) << 3) + xcd) * 128;
    int n0 = (j >> 3) * 128;

    f32x4 acc[4][4];
    #pragma unroll
    for (int i = 0; i < 4; i++)
        #pragma unroll
        for (int jj = 0; jj < 4; jj++) acc[i][jj] = (f32x4){0.f, 0.f, 0.f, 0.f};

    int r0 = tid >> 3, cg = tid & 7;
    int g = cg ^ (r0 & 7);
    const u16* GA[4]; const u16* GB[4];
    #pragma unroll
    for (int it = 0; it < 4; it++) {
        int m = m0 + it * 32 + r0, b = m >> 10, npos = m & 1023;
        GA[it] = Qg + (((size_t)(b * 12) * 1024 + npos) << 6) + g * 8;  // + h*65536
        GB[it] = Bt + (size_t)(n0 + it * 32 + r0) * K + g * 8;          // + kt
    }

    #define STAGE_OUT(i2, b)                                              \
        _Pragma("unroll")                                                 \
        for (int it = 0; it < 4; it++) {                                  \
            cp16(GA[it] + (size_t)(i2) * 65536, &As[b][(it * 256 + tid) * 8]); \
            cp16(GB[it] + (i2) * 64,            &Bs[b][(it * 256 + tid) * 8]); \
        }

    STAGE_OUT(0, 0)
    for (int i = 0; i < 12; i++) {
        int b = i & 1;
        __syncthreads();
        if (i + 1 < 12) { STAGE_OUT(i + 1, b ^ 1) }
        bf16x8 af[2][4], bfr[2][4];
        #pragma unroll
        for (int ko = 0; ko < 2; ko++)
            #pragma unroll
            for (int x = 0; x < 4; x++) {
                int Ra = wm * 64 + x * 16 + l16;
                af[ko][x]  = *(const bf16x8*)&As[b][Ra * 64 + (((ko * 4 + quad) ^ (Ra & 7)) * 8)];
                int Rb = wn * 64 + x * 16 + l16;
                bfr[ko][x] = *(const bf16x8*)&Bs[b][Rb * 64 + (((ko * 4 + quad) ^ (Rb & 7)) * 8)];
            }
        #pragma unroll
        for (int ko = 0; ko < 2; ko++)
            #pragma unroll
            for (int x = 0; x < 4; x++)
                #pragma unroll
                for (int y = 0; y < 4; y++)
                    acc[x][y] = __builtin_amdgcn_mfma_f32_16x16x32_bf16(af[ko][x], bfr[ko][y], acc[x][y], 0, 0, 0);
    }
    #undef STAGE_OUT

    #pragma unroll
    for (int i = 0; i < 4; i++) {
        int mbase = m0 + wm * 64 + i * 16 + quad * 4;
        #pragma unroll
        for (int jj = 0; jj < 4; jj++) {
            int n = n0 + wn * 64 + jj * 16 + l16;
            float bv = bias[n];
            #pragma unroll
            for (int r = 0; r < 4; r++)
                out[(size_t)(mbase + r) * 768 + n] = acc[i][jj][r] + bv;
        }
    }
}

extern "C" void kernel_launch(void* const* d_in, const int* in_sizes, int n_in,
                              void* d_out, int out_size, void* d_ws, size_t ws_size,
                              hipStream_t stream) {
    const float* x     = (const float*)d_in[0];   // [8,1024,768] f32
    const float* w_qkv = (const float*)d_in[1];   // [768,2304] f32
    const float* w_out = (const float*)d_in[2];   // [768,768] f32
    const float* b_out = (const float*)d_in[3];   // [768] f32
    float* out = (float*)d_out;                   // [8,1024,768] f32

    char* ws = (char*)d_ws;
    u16* wtq  = (u16*)(ws);                   // [2304][768] bf16    3,538,944 B
    u16* wto  = (u16*)(ws + 3538944);         // [768][768]  bf16    1,179,648 B
    u16* Qbuf = (u16*)(ws + 4718592);         // [8,12,1024,64] bf16 12,582,912 B
    u16* xbf  = (u16*)(ws + 17301504);        // [8192][768] bf16    12,582,912 B  (29.9 MB)
    // K natural [b,h,n,64] and V TRANSPOSED [b,h,64,n] live in d_out (2x12.58 MB);
    // both fully consumed by attn128 before gemm_out overwrites d_out.
    u16* Kbuf = (u16*)d_out;
    u16* Vbuf = (u16*)d_out + 6291456;

    prep<<<dim3(5376), 256, 0, stream>>>(x, w_qkv, w_out, xbf, wtq, wto);
    gemm_qkv<<<dim3(1152), 256, 0, stream>>>(xbf, wtq, Qbuf, Kbuf, Vbuf);
    attn128<<<dim3(768), 256, 0, stream>>>(Qbuf, Kbuf, Vbuf);
    gemm_out<<<dim3(384), 256, 0, stream>>>(Qbuf, wto, b_out, out);
}

// Round 9
// 190.784 us; speedup vs baseline: 1.0117x; 1.0117x over previous
//
#include <hip/hip_runtime.h>

typedef unsigned short u16;
typedef __bf16 bf16x8 __attribute__((ext_vector_type(8)));
typedef float f32x4 __attribute__((ext_vector_type(4)));

__device__ inline u16 f2bf(float f) {
    union { float f; unsigned int u; } a; a.f = f;
    unsigned int u = a.u + 0x7fffu + ((a.u >> 16) & 1u);
    return (u16)(u >> 16);
}
// truncate f32 -> bf16 bits; returns truncated value as f32
__device__ __forceinline__ float truncbf(float f, u16& h) {
    union { float f; unsigned int u; } a; a.f = f;
    a.u &= 0xffff0000u;
    h = (u16)(a.u >> 16);
    return a.f;
}

// async global->LDS, 16B per lane. LDS side is wave-uniform base + lane*16.
__device__ __forceinline__ void cp16(const void* g, void* l) {
    __builtin_amdgcn_global_load_lds(
        (const __attribute__((address_space(1))) unsigned int*)g,
        (__attribute__((address_space(3))) unsigned int*)l, 16, 0, 0);
}

// -------- prep: fuse x-cast + both weight transposes (1 launch) --------
__global__ __launch_bounds__(256) void prep(
    const float* __restrict__ x, const float* __restrict__ wq,
    const float* __restrict__ wo, u16* __restrict__ xbf,
    u16* __restrict__ wtq, u16* __restrict__ wto)
{
    int bid = blockIdx.x;
    if (bid < 3072) {                      // cast x: f32 -> bf16, 8/thread
        size_t base = ((size_t)bid * 256 + threadIdx.x) * 8;
        float4 f0 = *(const float4*)&x[base];
        float4 f1 = *(const float4*)&x[base + 4];
        union { u16 s[8]; uint4 v; } t;
        t.s[0]=f2bf(f0.x); t.s[1]=f2bf(f0.y); t.s[2]=f2bf(f0.z); t.s[3]=f2bf(f0.w);
        t.s[4]=f2bf(f1.x); t.s[5]=f2bf(f1.y); t.s[6]=f2bf(f1.z); t.s[7]=f2bf(f1.w);
        *(uint4*)&xbf[base] = t.v;
        return;
    }
    __shared__ u16 tile[32][33];
    const float* in; u16* outp; int N, bx, by;
    if (bid < 3072 + 1728) { int t = bid - 3072; in = wq; outp = wtq; N = 2304; bx = t % 72; by = t / 72; }
    else                   { int t = bid - 4800; in = wo; outp = wto; N = 768;  bx = t % 24; by = t / 24; }
    int n0 = bx * 32, k0 = by * 32;
    int tx = threadIdx.x & 31, ty = threadIdx.x >> 5;
    #pragma unroll
    for (int r = ty; r < 32; r += 8)
        tile[r][tx] = f2bf(in[(size_t)(k0 + r) * N + n0 + tx]);
    __syncthreads();
    #pragma unroll
    for (int r = ty; r < 32; r += 8)
        outp[(size_t)(n0 + r) * 768 + k0 + tx] = tile[tx][r];
}

// -------- QKV GEMM: BK=32 dbuf (32 KB LDS), FRAGS-FIRST, XCD-pinned --------
// LDS tile layout: logical row R (0..127) -> packed row r'=R&63 (128 B), slot
// s = ((R>>6)*4 + kgroup) ^ (r'&7). Conflict-free b128 frags, lane-order staging.
__global__ __launch_bounds__(256) void gemm_qkv(
    const u16* __restrict__ A, const u16* __restrict__ Bt,
    u16* __restrict__ q_out, u16* __restrict__ k_out, u16* __restrict__ v_out)
{
    const int K = 768;
    __shared__ __align__(16) u16 As[2][128 * 32];   // 8 KB per buffer
    __shared__ __align__(16) u16 Bs[2][128 * 32];

    int tid = threadIdx.x;
    int lane = tid & 63, wave = tid >> 6;
    int quad = lane >> 4, l16 = lane & 15;
    int wm = wave >> 1, wn = wave & 1;
    int id = blockIdx.x;
    int xcd = id & 7, j = id >> 3;
    int m0 = (((j & 7) << 3) + xcd) * 128;   // 64 m-tiles, XCD-pinned A slabs
    int n0 = (j >> 3) * 128;                 // 18 n-tiles

    f32x4 acc[4][4];
    #pragma unroll
    for (int i = 0; i < 4; i++)
        #pragma unroll
        for (int jj = 0; jj < 4; jj++) acc[i][jj] = (f32x4){0.f, 0.f, 0.f, 0.f};

    // staging decode: chunk c = it*256+tid -> r'=c>>3, t8=(c&7)^(r'&7), row=r'+64*(t8>>2), kgroup=t8&3
    const u16* GA[2]; const u16* GB[2];
    #pragma unroll
    for (int it = 0; it < 2; it++) {
        int c = it * 256 + tid;
        int rp = c >> 3;
        int t8 = (c & 7) ^ (rp & 7);
        int row = rp + 64 * (t8 >> 2), gk = t8 & 3;
        GA[it] = A  + (size_t)(m0 + row) * K + gk * 8;
        GB[it] = Bt + (size_t)(n0 + row) * K + gk * 8;
    }

    #define STG(kt, b)                                              \
        _Pragma("unroll")                                           \
        for (int it = 0; it < 2; it++) {                            \
            cp16(GA[it] + (kt), &As[b][(it * 256 + tid) * 8]);      \
            cp16(GB[it] + (kt), &Bs[b][(it * 256 + tid) * 8]);      \
        }

    STG(0, 0)
    for (int i = 0; i < 24; i++) {
        int b = i & 1;
        __syncthreads();                              // drains buf-b loads
        bf16x8 af[4], bfr[4];                         // frags FIRST (no vmem since barrier)
        #pragma unroll
        for (int x = 0; x < 4; x++) {
            int Ra = wm * 64 + x * 16 + l16, ra = Ra & 63;
            int sa = (((Ra >> 6) << 2) + quad) ^ (ra & 7);
            af[x] = *(const bf16x8*)&As[b][ra * 64 + sa * 8];
            int Rb = wn * 64 + x * 16 + l16, rb = Rb & 63;
            int sb = (((Rb >> 6) << 2) + quad) ^ (rb & 7);
            bfr[x] = *(const bf16x8*)&Bs[b][rb * 64 + sb * 8];
        }
        if (i + 1 < 24) { STG((i + 1) * 32, b ^ 1) }  // prefetch flies across MFMAs
        #pragma unroll
        for (int x = 0; x < 4; x++)
            #pragma unroll
            for (int y = 0; y < 4; y++)
                acc[x][y] = __builtin_amdgcn_mfma_f32_16x16x32_bf16(af[x], bfr[y], acc[x][y], 0, 0, 0);
    }
    #undef STG
    __syncthreads();   // all frag reads done before buffers become epilogue scratch

    // ---- epilogue: wave tile = 64m x 64n, one (part,h); per-wave 8 KB LDS region ----
    int M0 = m0 + wm * 64, N0 = n0 + wn * 64;
    int part = N0 >= 1536 ? 2 : (N0 >= 768 ? 1 : 0);
    int h = (N0 - part * 768) >> 6;
    int b2 = M0 >> 10, npos0 = M0 & 1023;
    u16* ep = (wave & 2) ? &Bs[wave & 1][0] : &As[wave & 1][0];

    if (part != 2) {
        float scale = (part == 0) ? 0.18033688011112042f : 1.0f;   // /8 * log2e for Q
        u16* gbase = (part == 0 ? q_out : k_out) + (((size_t)(b2 * 12 + h) * 1024 + npos0) << 6);
        #pragma unroll
        for (int i = 0; i < 4; i++)
            #pragma unroll
            for (int jj = 0; jj < 4; jj++) {
                int dd = jj * 16 + l16;
                #pragma unroll
                for (int r = 0; r < 4; r++) {
                    int np = i * 16 + quad * 4 + r;
                    ep[np * 64 + (((dd >> 3) ^ (np & 7)) * 8) + (dd & 7)] =
                        f2bf(acc[i][jj][r] * scale);
                }
            }
        #pragma unroll
        for (int t = 0; t < 8; t++) {        // per-wave region: ds order suffices
            int idx = t * 512 + lane * 8;
            int np = idx >> 6;
            int slot = ((lane & 7) ^ (np & 7));
            uint4 v = *(const uint4*)&ep[np * 64 + slot * 8];
            *(uint4*)&gbase[idx] = v;
        }
    } else {
        #pragma unroll
        for (int i = 0; i < 4; i++)
            #pragma unroll
            for (int jj = 0; jj < 4; jj++) {
                int dd = jj * 16 + l16;
                int npg = i * 2 + (quad >> 1);
                int sub = (quad & 1) * 4;
                union { u16 s[4]; uint2 v; } pk;
                #pragma unroll
                for (int r = 0; r < 4; r++) pk.s[r] = f2bf(acc[i][jj][r]);
                *(uint2*)&ep[dd * 64 + ((npg ^ (dd & 7)) * 8) + sub] = pk.v;
            }
        #pragma unroll
        for (int t = 0; t < 8; t++) {
            int dd = t * 8 + (lane >> 3);
            int npg = lane & 7;
            uint4 v = *(const uint4*)&ep[dd * 64 + ((npg ^ (dd & 7)) * 8)];
            *(uint4*)&v_out[((size_t)((b2 * 12 + h) * 64 + dd)) * 1024 + npos0 + npg * 8] = v;
        }
    }
}

// -------- attention: S^T form, 128 q/block, dbuf FRAGS-FIRST, XCD-pinned heads --------
__global__ __launch_bounds__(256) void attn128(
    u16* __restrict__ QO, const u16* __restrict__ Kg, const u16* __restrict__ Vtg)
{
    __shared__ __align__(16) u16 Ks[2][64 * 64];   // [kv][d], groups XOR-swizzled
    __shared__ __align__(16) u16 Vs[2][64 * 64];   // [d][kv], groups XOR-swizzled

    int tid = threadIdx.x;
    int lane = tid & 63, wave = tid >> 6;
    int quad = lane >> 4, l16 = lane & 15;
    int id = blockIdx.x;
    int xcd = id & 7, j = id >> 3;              // 12 heads per XCD
    int bh = xcd * 12 + (j >> 3);
    int q0 = (j & 7) * 128;
    const size_t head_base = (size_t)bh * 65536;

    size_t qoff[2];
    bf16x8 qf[2][2];
    #pragma unroll
    for (int qs = 0; qs < 2; qs++) {
        qoff[qs] = head_base + (size_t)(q0 + wave * 32 + qs * 16 + l16) * 64;
        qf[qs][0] = *(const bf16x8*)&QO[qoff[qs] + quad * 8];
        qf[qs][1] = *(const bf16x8*)&QO[qoff[qs] + 32 + quad * 8];
    }

    f32x4 Oacc[4][2];
    #pragma unroll
    for (int dt = 0; dt < 4; dt++)
        #pragma unroll
        for (int qs = 0; qs < 2; qs++) Oacc[dt][qs] = (f32x4){0.f, 0.f, 0.f, 0.f};
    float l_part[2] = {0.f, 0.f};

    int srow = tid >> 3, sg = tid & 7;
    int gs = sg ^ (srow & 7);
    const u16* GK[2]; const u16* GV[2];
    #pragma unroll
    for (int it = 0; it < 2; it++) {
        GK[it] = Kg  + head_base + (size_t)(it * 32 + srow) * 64 + gs * 8;
        GV[it] = Vtg + head_base + (size_t)(it * 32 + srow) * 1024 + gs * 8;
    }

    #define STAGE_ATT(j0, b)                                          \
        _Pragma("unroll")                                             \
        for (int it = 0; it < 2; it++) {                              \
            cp16(GK[it] + (size_t)(j0) * 64, &Ks[b][(it * 256 + tid) * 8]); \
            cp16(GV[it] + (j0),             &Vs[b][(it * 256 + tid) * 8]); \
        }

    STAGE_ATT(0, 0)
    for (int i = 0; i < 16; i++) {
        int b = i & 1;
        __syncthreads();
        bf16x8 kf[4][2];                      // K fragments FIRST
        #pragma unroll
        for (int nt = 0; nt < 4; nt++) {
            int R = nt * 16 + l16;
            kf[nt][0] = *(const bf16x8*)&Ks[b][R * 64 + ((quad       ^ (R & 7)) * 8)];
            kf[nt][1] = *(const bf16x8*)&Ks[b][R * 64 + (((quad + 4) ^ (R & 7)) * 8)];
        }
        if (i + 1 < 16) { STAGE_ATT((i + 1) * 64, b ^ 1) }

        f32x4 s4[4][2];
        #pragma unroll
        for (int nt = 0; nt < 4; nt++)
            #pragma unroll
            for (int qs = 0; qs < 2; qs++) {
                f32x4 s = (f32x4){0.f, 0.f, 0.f, 0.f};
                s = __builtin_amdgcn_mfma_f32_16x16x32_bf16(kf[nt][0], qf[qs][0], s, 0, 0, 0);
                s = __builtin_amdgcn_mfma_f32_16x16x32_bf16(kf[nt][1], qf[qs][1], s, 0, 0, 0);
                s4[nt][qs] = s;
            }

        // p = 2^s, truncated to bf16; l sums the SAME truncated values
        u16 ph[4][2][4];
        #pragma unroll
        for (int nt = 0; nt < 4; nt++)
            #pragma unroll
            for (int qs = 0; qs < 2; qs++)
                #pragma unroll
                for (int r = 0; r < 4; r++) {
                    float p = __builtin_amdgcn_exp2f(s4[nt][qs][r]);
                    l_part[qs] += truncbf(p, ph[nt][qs][r]);
                }

        #pragma unroll
        for (int h = 0; h < 2; h++) {
            union { u16 s[8]; bf16x8 v; } pk[2];
            #pragma unroll
            for (int qs = 0; qs < 2; qs++)
                #pragma unroll
                for (int r = 0; r < 4; r++) {
                    pk[qs].s[r]     = ph[2 * h][qs][r];
                    pk[qs].s[4 + r] = ph[2 * h + 1][qs][r];
                }
            int lg0 = 4 * h + (quad >> 1), lg1 = lg0 + 2;
            int off = (quad & 1) * 4;
            #pragma unroll
            for (int dt = 0; dt < 4; dt++) {
                int drow = dt * 16 + l16;
                union { u16 s[8]; bf16x8 v; } vk;
                *(uint2*)&vk.s[0] = *(const uint2*)&Vs[b][drow * 64 + (lg0 ^ (drow & 7)) * 8 + off];
                *(uint2*)&vk.s[4] = *(const uint2*)&Vs[b][drow * 64 + (lg1 ^ (drow & 7)) * 8 + off];
                #pragma unroll
                for (int qs = 0; qs < 2; qs++)
                    Oacc[dt][qs] = __builtin_amdgcn_mfma_f32_16x16x32_bf16(vk.v, pk[qs].v, Oacc[dt][qs], 0, 0, 0);
            }
        }
    }
    #undef STAGE_ATT

    #pragma unroll
    for (int qs = 0; qs < 2; qs++) {
        float l = l_part[qs];
        l += __shfl_xor(l, 16);
        l += __shfl_xor(l, 32);
        float rl = __builtin_amdgcn_rcpf(l);
        #pragma unroll
        for (int dt = 0; dt < 4; dt++) {
            union { u16 s[4]; uint2 v; } ok;
            #pragma unroll
            for (int r = 0; r < 4; r++) ok.s[r] = f2bf(Oacc[dt][qs][r] * rl);
            *(uint2*)&QO[qoff[qs] + dt * 16 + quad * 4] = ok.v;
        }
    }
}

// -------- out-proj GEMM: BK=64 dbuf, FRAGS-FIRST, XCD-pinned --------
__global__ __launch_bounds__(256) void gemm_out(
    const u16* __restrict__ Qg, const u16* __restrict__ Bt,
    const float* __restrict__ bias, float* __restrict__ out)
{
    const int K = 768;
    __shared__ __align__(16) u16 As[2][128 * 64];
    __shared__ __align__(16) u16 Bs[2][128 * 64];

    int tid = threadIdx.x;
    int lane = tid & 63, wave = tid >> 6;
    int quad = lane >> 4, l16 = lane & 15;
    int wm = wave >> 1, wn = wave & 1;
    int id = blockIdx.x;
    int xcd = id & 7, j = id >> 3;
    int m0 = (((j & 7) << 3) + xcd) * 128;
    int n0 = (j >> 3) * 128;

    f32x4 acc[4][4];
    #pragma unroll
    for (int i = 0; i < 4; i++)
        #pragma unroll
        for (int jj = 0; jj < 4; jj++) acc[i][jj] = (f32x4){0.f, 0.f, 0.f, 0.f};

    int r0 = tid >> 3, cg = tid & 7;
    int g = cg ^ (r0 & 7);
    const u16* GA[4]; const u16* GB[4];
    #pragma unroll
    for (int it = 0; it < 4; it++) {
        int m = m0 + it * 32 + r0, b = m >> 10, npos = m & 1023;
        GA[it] = Qg + (((size_t)(b * 12) * 1024 + npos) << 6) + g * 8;  // + h*65536
        GB[it] = Bt + (size_t)(n0 + it * 32 + r0) * K + g * 8;          // + kt
    }

    #define STAGE_OUT(i2, b)                                              \
        _Pragma("unroll")                                                 \
        for (int it = 0; it < 4; it++) {                                  \
            cp16(GA[it] + (size_t)(i2) * 65536, &As[b][(it * 256 + tid) * 8]); \
            cp16(GB[it] + (i2) * 64,            &Bs[b][(it * 256 + tid) * 8]); \
        }

    STAGE_OUT(0, 0)
    for (int i = 0; i < 12; i++) {
        int b = i & 1;
        __syncthreads();
        bf16x8 af[2][4], bfr[2][4];           // frags FIRST
        #pragma unroll
        for (int ko = 0; ko < 2; ko++)
            #pragma unroll
            for (int x = 0; x < 4; x++) {
                int Ra = wm * 64 + x * 16 + l16;
                af[ko][x]  = *(const bf16x8*)&As[b][Ra * 64 + (((ko * 4 + quad) ^ (Ra & 7)) * 8)];
                int Rb = wn * 64 + x * 16 + l16;
                bfr[ko][x] = *(const bf16x8*)&Bs[b][Rb * 64 + (((ko * 4 + quad) ^ (Rb & 7)) * 8)];
            }
        if (i + 1 < 12) { STAGE_OUT(i + 1, b ^ 1) }
        #pragma unroll
        for (int ko = 0; ko < 2; ko++)
            #pragma unroll
            for (int x = 0; x < 4; x++)
                #pragma unroll
                for (int y = 0; y < 4; y++)
                    acc[x][y] = __builtin_amdgcn_mfma_f32_16x16x32_bf16(af[ko][x], bfr[ko][y], acc[x][y], 0, 0, 0);
    }
    #undef STAGE_OUT

    #pragma unroll
    for (int i = 0; i < 4; i++) {
        int mbase = m0 + wm * 64 + i * 16 + quad * 4;
        #pragma unroll
        for (int jj = 0; jj < 4; jj++) {
            int n = n0 + wn * 64 + jj * 16 + l16;
            float bv = bias[n];
            #pragma unroll
            for (int r = 0; r < 4; r++)
                out[(size_t)(mbase + r) * 768 + n] = acc[i][jj][r] + bv;
        }
    }
}

extern "C" void kernel_launch(void* const* d_in, const int* in_sizes, int n_in,
                              void* d_out, int out_size, void* d_ws, size_t ws_size,
                              hipStream_t stream) {
    const float* x     = (const float*)d_in[0];   // [8,1024,768] f32
    const float* w_qkv = (const float*)d_in[1];   // [768,2304] f32
    const float* w_out = (const float*)d_in[2];   // [768,768] f32
    const float* b_out = (const float*)d_in[3];   // [768] f32
    float* out = (float*)d_out;                   // [8,1024,768] f32

    char* ws = (char*)d_ws;
    u16* wtq  = (u16*)(ws);                   // [2304][768] bf16    3,538,944 B
    u16* wto  = (u16*)(ws + 3538944);         // [768][768]  bf16    1,179,648 B
    u16* Qbuf = (u16*)(ws + 4718592);         // [8,12,1024,64] bf16 12,582,912 B
    u16* xbf  = (u16*)(ws + 17301504);        // [8192][768] bf16    12,582,912 B  (29.9 MB)
    // K natural [b,h,n,64] and V TRANSPOSED [b,h,64,n] live in d_out (2x12.58 MB);
    // both fully consumed by attn128 before gemm_out overwrites d_out.
    u16* Kbuf = (u16*)d_out;
    u16* Vbuf = (u16*)d_out + 6291456;

    prep<<<dim3(5376), 256, 0, stream>>>(x, w_qkv, w_out, xbf, wtq, wto);
    gemm_qkv<<<dim3(1152), 256, 0, stream>>>(xbf, wtq, Qbuf, Kbuf, Vbuf);
    attn128<<<dim3(768), 256, 0, stream>>>(Qbuf, Kbuf, Vbuf);
    gemm_out<<<dim3(384), 256, 0, stream>>>(Qbuf, wto, b_out, out);
}

// Round 10
// 183.815 us; speedup vs baseline: 1.0501x; 1.0379x over previous
//
#include <hip/hip_runtime.h>

typedef unsigned short u16;
typedef __bf16 bf16x8 __attribute__((ext_vector_type(8)));
typedef float f32x4 __attribute__((ext_vector_type(4)));

__device__ inline u16 f2bf(float f) {
    union { float f; unsigned int u; } a; a.f = f;
    unsigned int u = a.u + 0x7fffu + ((a.u >> 16) & 1u);
    return (u16)(u >> 16);
}
// truncate f32 -> bf16 bits; returns truncated value as f32
__device__ __forceinline__ float truncbf(float f, u16& h) {
    union { float f; unsigned int u; } a; a.f = f;
    a.u &= 0xffff0000u;
    h = (u16)(a.u >> 16);
    return a.f;
}

// async global->LDS, 16B per lane. LDS side is wave-uniform base + lane*16.
__device__ __forceinline__ void cp16(const void* g, void* l) {
    __builtin_amdgcn_global_load_lds(
        (const __attribute__((address_space(1))) unsigned int*)g,
        (__attribute__((address_space(3))) unsigned int*)l, 16, 0, 0);
}

// -------- prep: fuse x-cast + both weight transposes (1 launch) --------
__global__ __launch_bounds__(256) void prep(
    const float* __restrict__ x, const float* __restrict__ wq,
    const float* __restrict__ wo, u16* __restrict__ xbf,
    u16* __restrict__ wtq, u16* __restrict__ wto)
{
    int bid = blockIdx.x;
    if (bid < 3072) {                      // cast x: f32 -> bf16, 8/thread
        size_t base = ((size_t)bid * 256 + threadIdx.x) * 8;
        float4 f0 = *(const float4*)&x[base];
        float4 f1 = *(const float4*)&x[base + 4];
        union { u16 s[8]; uint4 v; } t;
        t.s[0]=f2bf(f0.x); t.s[1]=f2bf(f0.y); t.s[2]=f2bf(f0.z); t.s[3]=f2bf(f0.w);
        t.s[4]=f2bf(f1.x); t.s[5]=f2bf(f1.y); t.s[6]=f2bf(f1.z); t.s[7]=f2bf(f1.w);
        *(uint4*)&xbf[base] = t.v;
        return;
    }
    __shared__ u16 tile[32][33];
    const float* in; u16* outp; int N, bx, by;
    if (bid < 3072 + 1728) { int t = bid - 3072; in = wq; outp = wtq; N = 2304; bx = t % 72; by = t / 72; }
    else                   { int t = bid - 4800; in = wo; outp = wto; N = 768;  bx = t % 24; by = t / 24; }
    int n0 = bx * 32, k0 = by * 32;
    int tx = threadIdx.x & 31, ty = threadIdx.x >> 5;
    #pragma unroll
    for (int r = ty; r < 32; r += 8)
        tile[r][tx] = f2bf(in[(size_t)(k0 + r) * N + n0 + tx]);
    __syncthreads();
    #pragma unroll
    for (int r = ty; r < 32; r += 8)
        outp[(size_t)(n0 + r) * 768 + k0 + tx] = tile[tx][r];
}

// -------- QKV GEMM: BK=32 dbuf (32 KB LDS), FULLY UNROLLED K-loop, XCD-pinned --------
// LDS tile layout: logical row R (0..127) -> packed row r'=R&63 (128 B), slot
// s = ((R>>6)*4 + kgroup) ^ (r'&7). Conflict-free b128 frags, lane-order staging.
__global__ __launch_bounds__(256) void gemm_qkv(
    const u16* __restrict__ A, const u16* __restrict__ Bt,
    u16* __restrict__ q_out, u16* __restrict__ k_out, u16* __restrict__ v_out)
{
    const int K = 768;
    __shared__ __align__(16) u16 As[2][128 * 32];   // 8 KB per buffer
    __shared__ __align__(16) u16 Bs[2][128 * 32];

    int tid = threadIdx.x;
    int lane = tid & 63, wave = tid >> 6;
    int quad = lane >> 4, l16 = lane & 15;
    int wm = wave >> 1, wn = wave & 1;
    int id = blockIdx.x;
    int xcd = id & 7, j = id >> 3;
    int m0 = (((j & 7) << 3) + xcd) * 128;   // 64 m-tiles, XCD-pinned A slabs
    int n0 = (j >> 3) * 128;                 // 18 n-tiles

    f32x4 acc[4][4];
    #pragma unroll
    for (int i = 0; i < 4; i++)
        #pragma unroll
        for (int jj = 0; jj < 4; jj++) acc[i][jj] = (f32x4){0.f, 0.f, 0.f, 0.f};

    // staging decode: chunk c = it*256+tid -> r'=c>>3, t8=(c&7)^(r'&7), row=r'+64*(t8>>2), kgroup=t8&3
    const u16* GA[2]; const u16* GB[2];
    #pragma unroll
    for (int it = 0; it < 2; it++) {
        int c = it * 256 + tid;
        int rp = c >> 3;
        int t8 = (c & 7) ^ (rp & 7);
        int row = rp + 64 * (t8 >> 2), gk = t8 & 3;
        GA[it] = A  + (size_t)(m0 + row) * K + gk * 8;
        GB[it] = Bt + (size_t)(n0 + row) * K + gk * 8;
    }

    // LDS fragment addresses (constant per buffer)
    int aoffs[4], boffs[4];
    #pragma unroll
    for (int x = 0; x < 4; x++) {
        int Ra = wm * 64 + x * 16 + l16, ra = Ra & 63;
        aoffs[x] = ra * 64 + ((((Ra >> 6) << 2) + quad) ^ (ra & 7)) * 8;
        int Rb = wn * 64 + x * 16 + l16, rb = Rb & 63;
        boffs[x] = rb * 64 + ((((Rb >> 6) << 2) + quad) ^ (rb & 7)) * 8;
    }

    #define STG(kt, b)                                              \
        _Pragma("unroll")                                           \
        for (int it = 0; it < 2; it++) {                            \
            cp16(GA[it] + (kt), &As[b][(it * 256 + tid) * 8]);      \
            cp16(GB[it] + (kt), &Bs[b][(it * 256 + tid) * 8]);      \
        }

    STG(0, 0)
    #pragma unroll                                   // kt, buffer index -> compile-time
    for (int i = 0; i < 24; i++) {
        const int b = i & 1;
        __syncthreads();                              // drains buf-b loads
        bf16x8 af[4], bfr[4];                         // frags FIRST (no vmem since barrier)
        #pragma unroll
        for (int x = 0; x < 4; x++) {
            af[x]  = *(const bf16x8*)&As[b][aoffs[x]];
            bfr[x] = *(const bf16x8*)&Bs[b][boffs[x]];
        }
        if (i + 1 < 24) { STG((i + 1) * 32, b ^ 1) }  // imm-folded offsets, flies across MFMAs
        #pragma unroll
        for (int x = 0; x < 4; x++)
            #pragma unroll
            for (int y = 0; y < 4; y++)
                acc[x][y] = __builtin_amdgcn_mfma_f32_16x16x32_bf16(af[x], bfr[y], acc[x][y], 0, 0, 0);
    }
    #undef STG
    __syncthreads();   // all frag reads done before buffers become epilogue scratch

    // ---- epilogue: wave tile = 64m x 64n, one (part,h); per-wave 8 KB LDS region ----
    int M0 = m0 + wm * 64, N0 = n0 + wn * 64;
    int part = N0 >= 1536 ? 2 : (N0 >= 768 ? 1 : 0);
    int h = (N0 - part * 768) >> 6;
    int b2 = M0 >> 10, npos0 = M0 & 1023;
    u16* ep = (wave & 2) ? &Bs[wave & 1][0] : &As[wave & 1][0];

    if (part != 2) {
        float scale = (part == 0) ? 0.18033688011112042f : 1.0f;   // /8 * log2e for Q
        u16* gbase = (part == 0 ? q_out : k_out) + (((size_t)(b2 * 12 + h) * 1024 + npos0) << 6);
        #pragma unroll
        for (int i = 0; i < 4; i++)
            #pragma unroll
            for (int jj = 0; jj < 4; jj++) {
                int dd = jj * 16 + l16;
                #pragma unroll
                for (int r = 0; r < 4; r++) {
                    int np = i * 16 + quad * 4 + r;
                    ep[np * 64 + (((dd >> 3) ^ (np & 7)) * 8) + (dd & 7)] =
                        f2bf(acc[i][jj][r] * scale);
                }
            }
        #pragma unroll
        for (int t = 0; t < 8; t++) {        // per-wave region: ds order suffices
            int idx = t * 512 + lane * 8;
            int np = idx >> 6;
            int slot = ((lane & 7) ^ (np & 7));
            uint4 v = *(const uint4*)&ep[np * 64 + slot * 8];
            *(uint4*)&gbase[idx] = v;
        }
    } else {
        #pragma unroll
        for (int i = 0; i < 4; i++)
            #pragma unroll
            for (int jj = 0; jj < 4; jj++) {
                int dd = jj * 16 + l16;
                int npg = i * 2 + (quad >> 1);
                int sub = (quad & 1) * 4;
                union { u16 s[4]; uint2 v; } pk;
                #pragma unroll
                for (int r = 0; r < 4; r++) pk.s[r] = f2bf(acc[i][jj][r]);
                *(uint2*)&ep[dd * 64 + ((npg ^ (dd & 7)) * 8) + sub] = pk.v;
            }
        #pragma unroll
        for (int t = 0; t < 8; t++) {
            int dd = t * 8 + (lane >> 3);
            int npg = lane & 7;
            uint4 v = *(const uint4*)&ep[dd * 64 + ((npg ^ (dd & 7)) * 8)];
            *(uint4*)&v_out[((size_t)((b2 * 12 + h) * 64 + dd)) * 1024 + npos0 + npg * 8] = v;
        }
    }
}

// -------- attention: S^T form, 128 q/block, dbuf frags-first, XCD-pinned heads --------
__global__ __launch_bounds__(256) void attn128(
    u16* __restrict__ QO, const u16* __restrict__ Kg, const u16* __restrict__ Vtg)
{
    __shared__ __align__(16) u16 Ks[2][64 * 64];   // [kv][d], groups XOR-swizzled
    __shared__ __align__(16) u16 Vs[2][64 * 64];   // [d][kv], groups XOR-swizzled

    int tid = threadIdx.x;
    int lane = tid & 63, wave = tid >> 6;
    int quad = lane >> 4, l16 = lane & 15;
    int id = blockIdx.x;
    int xcd = id & 7, j = id >> 3;              // 12 heads per XCD
    int bh = xcd * 12 + (j >> 3);
    int q0 = (j & 7) * 128;
    const size_t head_base = (size_t)bh * 65536;

    size_t qoff[2];
    bf16x8 qf[2][2];
    #pragma unroll
    for (int qs = 0; qs < 2; qs++) {
        qoff[qs] = head_base + (size_t)(q0 + wave * 32 + qs * 16 + l16) * 64;
        qf[qs][0] = *(const bf16x8*)&QO[qoff[qs] + quad * 8];
        qf[qs][1] = *(const bf16x8*)&QO[qoff[qs] + 32 + quad * 8];
    }

    f32x4 Oacc[4][2];
    #pragma unroll
    for (int dt = 0; dt < 4; dt++)
        #pragma unroll
        for (int qs = 0; qs < 2; qs++) Oacc[dt][qs] = (f32x4){0.f, 0.f, 0.f, 0.f};
    float l_part[2] = {0.f, 0.f};

    int srow = tid >> 3, sg = tid & 7;
    int gs = sg ^ (srow & 7);
    const u16* GK[2]; const u16* GV[2];
    #pragma unroll
    for (int it = 0; it < 2; it++) {
        GK[it] = Kg  + head_base + (size_t)(it * 32 + srow) * 64 + gs * 8;
        GV[it] = Vtg + head_base + (size_t)(it * 32 + srow) * 1024 + gs * 8;
    }

    #define STAGE_ATT(j0, b)                                          \
        _Pragma("unroll")                                             \
        for (int it = 0; it < 2; it++) {                              \
            cp16(GK[it] + (size_t)(j0) * 64, &Ks[b][(it * 256 + tid) * 8]); \
            cp16(GV[it] + (j0),             &Vs[b][(it * 256 + tid) * 8]); \
        }

    STAGE_ATT(0, 0)
    #pragma unroll 2
    for (int i = 0; i < 16; i++) {
        const int b = i & 1;
        __syncthreads();
        bf16x8 kf[4][2];                      // K fragments FIRST
        #pragma unroll
        for (int nt = 0; nt < 4; nt++) {
            int R = nt * 16 + l16;
            kf[nt][0] = *(const bf16x8*)&Ks[b][R * 64 + ((quad       ^ (R & 7)) * 8)];
            kf[nt][1] = *(const bf16x8*)&Ks[b][R * 64 + (((quad + 4) ^ (R & 7)) * 8)];
        }
        if (i + 1 < 16) { STAGE_ATT((i + 1) * 64, b ^ 1) }

        f32x4 s4[4][2];
        #pragma unroll
        for (int nt = 0; nt < 4; nt++)
            #pragma unroll
            for (int qs = 0; qs < 2; qs++) {
                f32x4 s = (f32x4){0.f, 0.f, 0.f, 0.f};
                s = __builtin_amdgcn_mfma_f32_16x16x32_bf16(kf[nt][0], qf[qs][0], s, 0, 0, 0);
                s = __builtin_amdgcn_mfma_f32_16x16x32_bf16(kf[nt][1], qf[qs][1], s, 0, 0, 0);
                s4[nt][qs] = s;
            }

        // p = 2^s, truncated to bf16; l sums the SAME truncated values
        u16 ph[4][2][4];
        #pragma unroll
        for (int nt = 0; nt < 4; nt++)
            #pragma unroll
            for (int qs = 0; qs < 2; qs++)
                #pragma unroll
                for (int r = 0; r < 4; r++) {
                    float p = __builtin_amdgcn_exp2f(s4[nt][qs][r]);
                    l_part[qs] += truncbf(p, ph[nt][qs][r]);
                }

        #pragma unroll
        for (int h = 0; h < 2; h++) {
            union { u16 s[8]; bf16x8 v; } pk[2];
            #pragma unroll
            for (int qs = 0; qs < 2; qs++)
                #pragma unroll
                for (int r = 0; r < 4; r++) {
                    pk[qs].s[r]     = ph[2 * h][qs][r];
                    pk[qs].s[4 + r] = ph[2 * h + 1][qs][r];
                }
            int lg0 = 4 * h + (quad >> 1), lg1 = lg0 + 2;
            int off = (quad & 1) * 4;
            #pragma unroll
            for (int dt = 0; dt < 4; dt++) {
                int drow = dt * 16 + l16;
                union { u16 s[8]; bf16x8 v; } vk;
                *(uint2*)&vk.s[0] = *(const uint2*)&Vs[b][drow * 64 + (lg0 ^ (drow & 7)) * 8 + off];
                *(uint2*)&vk.s[4] = *(const uint2*)&Vs[b][drow * 64 + (lg1 ^ (drow & 7)) * 8 + off];
                #pragma unroll
                for (int qs = 0; qs < 2; qs++)
                    Oacc[dt][qs] = __builtin_amdgcn_mfma_f32_16x16x32_bf16(vk.v, pk[qs].v, Oacc[dt][qs], 0, 0, 0);
            }
        }
    }
    #undef STAGE_ATT

    #pragma unroll
    for (int qs = 0; qs < 2; qs++) {
        float l = l_part[qs];
        l += __shfl_xor(l, 16);
        l += __shfl_xor(l, 32);
        float rl = __builtin_amdgcn_rcpf(l);
        #pragma unroll
        for (int dt = 0; dt < 4; dt++) {
            union { u16 s[4]; uint2 v; } ok;
            #pragma unroll
            for (int r = 0; r < 4; r++) ok.s[r] = f2bf(Oacc[dt][qs][r] * rl);
            *(uint2*)&QO[qoff[qs] + dt * 16 + quad * 4] = ok.v;
        }
    }
}

// -------- out-proj GEMM: BK=32 packed dbuf (32 KB), FULLY UNROLLED, XCD-pinned --------
__global__ __launch_bounds__(256) void gemm_out(
    const u16* __restrict__ Qg, const u16* __restrict__ Bt,
    const float* __restrict__ bias, float* __restrict__ out)
{
    const int K = 768;
    __shared__ __align__(16) u16 As[2][128 * 32];
    __shared__ __align__(16) u16 Bs[2][128 * 32];

    int tid = threadIdx.x;
    int lane = tid & 63, wave = tid >> 6;
    int quad = lane >> 4, l16 = lane & 15;
    int wm = wave >> 1, wn = wave & 1;
    int id = blockIdx.x;
    int xcd = id & 7, j = id >> 3;
    int m0 = (((j & 7) << 3) + xcd) * 128;
    int n0 = (j >> 3) * 128;

    f32x4 acc[4][4];
    #pragma unroll
    for (int i = 0; i < 4; i++)
        #pragma unroll
        for (int jj = 0; jj < 4; jj++) acc[i][jj] = (f32x4){0.f, 0.f, 0.f, 0.f};

    // packed staging decode (same as gemm_qkv); A gathered from [b,h,n,d]
    const u16* GA[2]; const u16* GB[2];
    #pragma unroll
    for (int it = 0; it < 2; it++) {
        int c = it * 256 + tid;
        int rp = c >> 3;
        int t8 = (c & 7) ^ (rp & 7);
        int row = rp + 64 * (t8 >> 2), gk = t8 & 3;
        int m = m0 + row, b = m >> 10, npos = m & 1023;
        GA[it] = Qg + (((size_t)(b * 12) * 1024 + npos) << 6) + gk * 8;  // + h*65536 + (kt&32)
        GB[it] = Bt + (size_t)(n0 + row) * K + gk * 8;                   // + kt
    }

    int aoffs[4], boffs[4];
    #pragma unroll
    for (int x = 0; x < 4; x++) {
        int Ra = wm * 64 + x * 16 + l16, ra = Ra & 63;
        aoffs[x] = ra * 64 + ((((Ra >> 6) << 2) + quad) ^ (ra & 7)) * 8;
        int Rb = wn * 64 + x * 16 + l16, rb = Rb & 63;
        boffs[x] = rb * 64 + ((((Rb >> 6) << 2) + quad) ^ (rb & 7)) * 8;
    }

    #define STO(kt, b)                                                            \
        _Pragma("unroll")                                                         \
        for (int it = 0; it < 2; it++) {                                          \
            cp16(GA[it] + ((kt) >> 6) * 65536 + ((kt) & 32),                      \
                 &As[b][(it * 256 + tid) * 8]);                                   \
            cp16(GB[it] + (kt), &Bs[b][(it * 256 + tid) * 8]);                    \
        }

    STO(0, 0)
    #pragma unroll
    for (int i = 0; i < 24; i++) {
        const int b = i & 1;
        __syncthreads();
        bf16x8 af[4], bfr[4];
        #pragma unroll
        for (int x = 0; x < 4; x++) {
            af[x]  = *(const bf16x8*)&As[b][aoffs[x]];
            bfr[x] = *(const bf16x8*)&Bs[b][boffs[x]];
        }
        if (i + 1 < 24) { STO((i + 1) * 32, b ^ 1) }
        #pragma unroll
        for (int x = 0; x < 4; x++)
            #pragma unroll
            for (int y = 0; y < 4; y++)
                acc[x][y] = __builtin_amdgcn_mfma_f32_16x16x32_bf16(af[x], bfr[y], acc[x][y], 0, 0, 0);
    }
    #undef STO

    #pragma unroll
    for (int i = 0; i < 4; i++) {
        int mbase = m0 + wm * 64 + i * 16 + quad * 4;
        #pragma unroll
        for (int jj = 0; jj < 4; jj++) {
            int n = n0 + wn * 64 + jj * 16 + l16;
            float bv = bias[n];
            #pragma unroll
            for (int r = 0; r < 4; r++)
                out[(size_t)(mbase + r) * 768 + n] = acc[i][jj][r] + bv;
        }
    }
}

extern "C" void kernel_launch(void* const* d_in, const int* in_sizes, int n_in,
                              void* d_out, int out_size, void* d_ws, size_t ws_size,
                              hipStream_t stream) {
    const float* x     = (const float*)d_in[0];   // [8,1024,768] f32
    const float* w_qkv = (const float*)d_in[1];   // [768,2304] f32
    const float* w_out = (const float*)d_in[2];   // [768,768] f32
    const float* b_out = (const float*)d_in[3];   // [768] f32
    float* out = (float*)d_out;                   // [8,1024,768] f32

    char* ws = (char*)d_ws;
    u16* wtq  = (u16*)(ws);                   // [2304][768] bf16    3,538,944 B
    u16* wto  = (u16*)(ws + 3538944);         // [768][768]  bf16    1,179,648 B
    u16* Qbuf = (u16*)(ws + 4718592);         // [8,12,1024,64] bf16 12,582,912 B
    u16* xbf  = (u16*)(ws + 17301504);        // [8192][768] bf16    12,582,912 B  (29.9 MB)
    // K natural [b,h,n,64] and V TRANSPOSED [b,h,64,n] live in d_out (2x12.58 MB);
    // both fully consumed by attn128 before gemm_out overwrites d_out.
    u16* Kbuf = (u16*)d_out;
    u16* Vbuf = (u16*)d_out + 6291456;

    prep<<<dim3(5376), 256, 0, stream>>>(x, w_qkv, w_out, xbf, wtq, wto);
    gemm_qkv<<<dim3(1152), 256, 0, stream>>>(xbf, wtq, Qbuf, Kbuf, Vbuf);
    attn128<<<dim3(768), 256, 0, stream>>>(Qbuf, Kbuf, Vbuf);
    gemm_out<<<dim3(384), 256, 0, stream>>>(Qbuf, wto, b_out, out);
}